// Round 1
// baseline (463.082 us; speedup 1.0000x reference)
//
#include <hip/hip_runtime.h>

#define HWPIX 589824
#define Hdim 768
#define Wdim 768
#define Bdim 4
#define Kdim 16
#define NBINS 2048
#define RANGE_F 16.0f
#define BIN_W (RANGE_F / NBINS)
#define INV_BIN_W (NBINS / RANGE_F)
#define EPSf 1e-6f

// ws float offsets
#define ACC_OFF 0        // B*K*5 = 320 floats: count, sum_emb_y, sum_emb_x, sum_sig_y, sum_sig_x
#define CK_OFF 320       // B*K*2
#define MS_OFF 448       // B*K*2
#define PRES_OFF 576     // B*K
#define NPRES_OFF 640
#define DEV_OFF 641      // B*K
#define SEED_OFF 705
#define LOV_OFF 706
#define HIST_OFF_F 768   // uint32 hist[B*K][2][NBINS] starts here
#define WS_ZERO_BYTES (768 * 4 + Bdim * Kdim * 2 * NBINS * 4)

__global__ void k_stats(const float* __restrict__ yp, const int* __restrict__ yt,
                        float* __restrict__ ws) {
    int b = blockIdx.y;
    int hw = blockIdx.x * blockDim.x + threadIdx.x;
    __shared__ float lacc[Kdim * 5];
    if (threadIdx.x < Kdim * 5) lacc[threadIdx.x] = 0.f;
    __syncthreads();
    int t = yt[(size_t)b * HWPIX + hw];
    if (t >= 1 && t <= Kdim) {
        int k = t - 1;
        const float* base = yp + (size_t)b * 5 * HWPIX + hw;
        float offy = base[0];
        float offx = base[HWPIX];
        float sy = base[2 * HWPIX];
        float sx = base[3 * HWPIX];
        int h = hw / Wdim;
        int w = hw - h * Wdim;
        atomicAdd(&lacc[k * 5 + 0], 1.0f);
        atomicAdd(&lacc[k * 5 + 1], (float)h + offy);
        atomicAdd(&lacc[k * 5 + 2], (float)w + offx);
        atomicAdd(&lacc[k * 5 + 3], sy);
        atomicAdd(&lacc[k * 5 + 4], sx);
    }
    __syncthreads();
    if (threadIdx.x < Kdim * 5) {
        float v = lacc[threadIdx.x];
        if (v != 0.f) atomicAdd(&ws[ACC_OFF + b * Kdim * 5 + threadIdx.x], v);
    }
}

__global__ void k_centers(float* __restrict__ ws) {
    int i = threadIdx.x;  // 0..63 = b*K+k
    float cnt = ws[ACC_OFF + i * 5];
    float safe = fmaxf(cnt, 1.0f);
    ws[CK_OFF + i * 2 + 0] = ws[ACC_OFF + i * 5 + 1] / safe;
    ws[CK_OFF + i * 2 + 1] = ws[ACC_OFF + i * 5 + 2] / safe;
    ws[MS_OFF + i * 2 + 0] = ws[ACC_OFF + i * 5 + 3] / safe;
    ws[MS_OFF + i * 2 + 1] = ws[ACC_OFF + i * 5 + 4] / safe;
    ws[PRES_OFF + i] = (cnt > 0.f) ? 1.f : 0.f;
    __syncthreads();
    if (i == 0) {
        float s = 0.f;
        for (int j = 0; j < Bdim * Kdim; ++j) s += ws[PRES_OFF + j];
        ws[NPRES_OFF] = fmaxf(s, 1.0f);
    }
}

__global__ void k_main(const float* __restrict__ yp, const int* __restrict__ yt,
                       float* __restrict__ ws, unsigned* __restrict__ hist) {
    int b = blockIdx.y;
    int hw = blockIdx.x * blockDim.x + threadIdx.x;
    int lane = threadIdx.x & 63;
    __shared__ float ck_s[32], ms_s[32], devs[16];
    __shared__ float red[256];
    if (threadIdx.x < 32) {
        ck_s[threadIdx.x] = ws[CK_OFF + b * 32 + threadIdx.x];
        ms_s[threadIdx.x] = ws[MS_OFF + b * 32 + threadIdx.x];
    }
    if (threadIdx.x < 16) devs[threadIdx.x] = 0.f;
    __syncthreads();

    const float* base = yp + (size_t)b * 5 * HWPIX + hw;
    float offy = base[0];
    float offx = base[HWPIX];
    float sy = base[2 * HWPIX];
    float sx = base[3 * HWPIX];
    float seed = base[4 * HWPIX];
    int t = yt[(size_t)b * HWPIX + hw];
    int own = t - 1;  // -1..15
    int h = hw / Wdim;
    int w = hw - h * Wdim;
    float ey = (float)h + offy, ex = (float)w + offx;
    float sby = fmaxf(sy, EPSf), sbx = fmaxf(sx, EPSf);
    float iy = 0.5f / (sby * sby), ix = 0.5f / (sbx * sbx);

    const float C_LO = logf(EPSf) - log1pf(-EPSf);  // logits at phi=EPS (~ -13.8155)
    const float E_HOT = 1.0f - C_LO;                // positive-label error at clamp
    const int HOTBIN = (int)(E_HOT * INV_BIN_W);

    unsigned* hb = hist + (size_t)(b * Kdim) * 2 * NBINS;
    float phi_own = 0.f;

    for (int k = 0; k < Kdim; ++k) {
        float dy = ey - ck_s[k * 2];
        float dx = ex - ck_s[k * 2 + 1];
        float q = dy * dy * iy + dx * dx * ix;
        float phi = expf(-q);
        phi = fminf(fmaxf(phi, EPSf), 1.0f - EPSf);
        float lg = logf(phi) - log1pf(-phi);
        bool isPos = (k == own);
        if (isPos) phi_own = phi;
        float e = isPos ? (1.0f - lg) : (1.0f + lg);
        int bin = (int)(e * INV_BIN_W);
        if (bin > NBINS - 1) bin = NBINS - 1;
        bool doAdd = (e > 0.f);
        bool hot = doAdd && isPos && (bin == HOTBIN);
        unsigned long long m = __ballot(hot);
        if (hot) {
            if ((__ffsll((unsigned long long)m) - 1) == lane)
                atomicAdd(&hb[(k * 2 + 1) * NBINS + HOTBIN], (unsigned)__popcll(m));
        } else if (doAdd) {
            atomicAdd(&hb[(k * 2 + (isPos ? 1 : 0)) * NBINS + bin], 1u);
        }
    }

    if (own >= 0) {
        float devv = fabsf(sy - ms_s[own * 2]) + fabsf(sx - ms_s[own * 2 + 1]);
        atomicAdd(&devs[own], devv);
    }
    float st = (own >= 0) ? phi_own : 0.f;
    float dd = seed - st;
    red[threadIdx.x] = dd * dd;
    __syncthreads();
    for (int s2 = 128; s2 > 0; s2 >>= 1) {
        if (threadIdx.x < s2) red[threadIdx.x] += red[threadIdx.x + s2];
        __syncthreads();
    }
    if (threadIdx.x == 0) atomicAdd(&ws[SEED_OFF], red[0]);
    if (threadIdx.x < 16) {
        float v = devs[threadIdx.x];
        if (v != 0.f) atomicAdd(&ws[DEV_OFF + b * Kdim + threadIdx.x], v);
    }
}

// One block (1 wave, 64 threads) per (b,k): suffix-scan the histogram top-down,
// trapezoid-integrate J(t) = 1 - (P - p(t))/(P + n(t)) over t in [0, RANGE].
__global__ void k_lovasz(float* __restrict__ ws, const unsigned* __restrict__ hist) {
    int i = blockIdx.x;  // 0..63
    int lane = threadIdx.x;
    float P = ws[ACC_OFF + i * 5];
    if (P < 0.5f) return;  // absent instance: lov * present == 0
    const unsigned* hn = hist + (size_t)i * 2 * NBINS;
    const unsigned* hp = hn + NBINS;
    int carry_p = 0, carry_n = 0;
    float Jtop = 0.f;  // J at the edge above the current chunk's top bucket
    float trap = 0.f;
    for (int c = NBINS / 64 - 1; c >= 0; --c) {
        int m = c * 64 + lane;
        int vp = (int)hp[m];
        int vn = (int)hn[m];
        // inclusive suffix-sum within wave
        for (int o = 1; o < 64; o <<= 1) {
            int tp = __shfl_down(vp, o);
            int tn = __shfl_down(vn, o);
            if (lane + o < 64) { vp += tp; vn += tn; }
        }
        float p_edge = (float)(carry_p + vp);
        float n_edge = (float)(carry_n + vn);
        float J = 1.0f - (P - p_edge) / (P + n_edge);
        float Jn = __shfl_down(J, 1);
        if (lane == 63) Jn = Jtop;
        trap += 0.5f * (J + Jn);
        carry_p += __shfl(vp, 0);
        carry_n += __shfl(vn, 0);
        Jtop = __shfl(J, 0);
    }
    for (int o = 1; o < 64; o <<= 1) {
        float t2 = __shfl_down(trap, o);
        if (lane + o < 64) trap += t2;
    }
    if (lane == 0) atomicAdd(&ws[LOV_OFF], trap * BIN_W);
}

__global__ void k_final(const float* __restrict__ ws, float* __restrict__ out) {
    float npres = ws[NPRES_OFF];
    float L_iou = ws[LOV_OFF] / npres;
    float lv = 0.f;
    for (int i = 0; i < Bdim * Kdim; ++i) {
        float cnt = ws[ACC_OFF + i * 5];
        if (cnt > 0.f) lv += ws[DEV_OFF + i] / (2.0f * cnt);
    }
    float L_var = lv / npres;
    float L_seed = ws[SEED_OFF] / (float)((size_t)Bdim * HWPIX);
    out[0] = L_iou + 10.0f * L_var + L_seed;
}

extern "C" void kernel_launch(void* const* d_in, const int* in_sizes, int n_in,
                              void* d_out, int out_size, void* d_ws, size_t ws_size,
                              hipStream_t stream) {
    const float* yp = (const float*)d_in[0];
    const int* yt = (const int*)d_in[1];
    float* ws = (float*)d_ws;
    unsigned* hist = (unsigned*)((char*)d_ws + HIST_OFF_F * 4);

    hipMemsetAsync(d_ws, 0, WS_ZERO_BYTES, stream);

    dim3 g(HWPIX / 256, Bdim);
    k_stats<<<g, 256, 0, stream>>>(yp, yt, ws);
    k_centers<<<1, 64, 0, stream>>>(ws);
    k_main<<<g, 256, 0, stream>>>(yp, yt, ws, hist);
    k_lovasz<<<64, 64, 0, stream>>>(ws, hist);
    k_final<<<1, 1, 0, stream>>>(ws, (float*)d_out);
}

// Round 2
// 140.754 us; speedup vs baseline: 3.2900x; 3.2900x over previous
//
#include <hip/hip_runtime.h>

#define HWPIX 589824
#define Hdim 768
#define Wdim 768
#define Bdim 4
#define Kdim 16
#define NBINS 2048
#define RANGE_F 16.0f
#define BIN_W (RANGE_F / NBINS)
#define INV_BIN_W (NBINS / RANGE_F)
#define EPSf 1e-6f
#define QCLIP 13.8155106f   /* -log(1e-6): q >= QCLIP  <=>  phi clamps to EPS */

// ws float offsets
#define ACC_OFF 0        // B*K*5: count, sum_emb_y, sum_emb_x, sum_sig_y, sum_sig_x
#define CK_OFF 320       // B*K*2
#define MS_OFF 448       // B*K*2
#define PRES_OFF 576     // B*K
#define NPRES_OFF 640
#define DEV_OFF 641      // B*K
#define SEED_OFF 705
#define LOV_OFF 706
#define HIST_OFF_F 768   // uint hist[B*K][2][NBINS], then uint posnh[B*K]
#define WS_ZERO_BYTES ((768 + Bdim * Kdim * 2 * NBINS + Bdim * Kdim) * 4)

#define SBLK 288         // blocks per batch for strided kernels
#define PPT 8            // pixels per thread (288*256*8 = 589824)
#define PSTRIDE (SBLK * 256)

__global__ void k_stats(const float* __restrict__ yp, const int* __restrict__ yt,
                        float* __restrict__ ws) {
    int b = blockIdx.y;
    int wv = threadIdx.x >> 6;
    __shared__ float lacc[4][Kdim * 5];
    for (int i = threadIdx.x; i < 4 * Kdim * 5; i += blockDim.x)
        ((float*)lacc)[i] = 0.f;
    __syncthreads();
    int tid = blockIdx.x * blockDim.x + threadIdx.x;
    const float* bp = yp + (size_t)b * 5 * HWPIX;
    const int* bt = yt + (size_t)b * HWPIX;
    for (int p = 0; p < PPT; ++p) {
        int hw = tid + p * PSTRIDE;
        int t = bt[hw];
        if (t >= 1 && t <= Kdim) {
            int k = t - 1;
            float offy = bp[hw];
            float offx = bp[hw + HWPIX];
            float sy = bp[hw + 2 * HWPIX];
            float sx = bp[hw + 3 * HWPIX];
            int h = hw / Wdim;
            int w = hw - h * Wdim;
            atomicAdd(&lacc[wv][k * 5 + 0], 1.0f);
            atomicAdd(&lacc[wv][k * 5 + 1], (float)h + offy);
            atomicAdd(&lacc[wv][k * 5 + 2], (float)w + offx);
            atomicAdd(&lacc[wv][k * 5 + 3], sy);
            atomicAdd(&lacc[wv][k * 5 + 4], sx);
        }
    }
    __syncthreads();
    if (threadIdx.x < Kdim * 5) {
        float v = lacc[0][threadIdx.x] + lacc[1][threadIdx.x] +
                  lacc[2][threadIdx.x] + lacc[3][threadIdx.x];
        if (v != 0.f) atomicAdd(&ws[ACC_OFF + b * Kdim * 5 + threadIdx.x], v);
    }
}

__global__ void k_centers(float* __restrict__ ws) {
    int i = threadIdx.x;  // 0..63 = b*K+k
    float cnt = ws[ACC_OFF + i * 5];
    float safe = fmaxf(cnt, 1.0f);
    ws[CK_OFF + i * 2 + 0] = ws[ACC_OFF + i * 5 + 1] / safe;
    ws[CK_OFF + i * 2 + 1] = ws[ACC_OFF + i * 5 + 2] / safe;
    ws[MS_OFF + i * 2 + 0] = ws[ACC_OFF + i * 5 + 3] / safe;
    ws[MS_OFF + i * 2 + 1] = ws[ACC_OFF + i * 5 + 4] / safe;
    ws[PRES_OFF + i] = (cnt > 0.f) ? 1.f : 0.f;
    __syncthreads();
    if (i == 0) {
        float s = 0.f;
        for (int j = 0; j < Bdim * Kdim; ++j) s += ws[PRES_OFF + j];
        ws[NPRES_OFF] = fmaxf(s, 1.0f);
    }
}

__global__ void k_main(const float* __restrict__ yp, const int* __restrict__ yt,
                       float* __restrict__ ws, unsigned* __restrict__ hist) {
    int b = blockIdx.y;
    int lane = threadIdx.x & 63;
    __shared__ float ck_s[32], ms_s[32], devs[16];
    __shared__ float seed_s;
    if (threadIdx.x < 32) {
        ck_s[threadIdx.x] = ws[CK_OFF + b * 32 + threadIdx.x];
        ms_s[threadIdx.x] = ws[MS_OFF + b * 32 + threadIdx.x];
    }
    if (threadIdx.x < 16) devs[threadIdx.x] = 0.f;
    if (threadIdx.x == 0) seed_s = 0.f;
    __syncthreads();

    // centers to registers for the unrolled fast loop
    float cky[Kdim], ckx[Kdim];
#pragma unroll
    for (int k = 0; k < Kdim; ++k) {
        cky[k] = ck_s[k * 2];
        ckx[k] = ck_s[k * 2 + 1];
    }

    unsigned* hb = hist + (size_t)(b * Kdim) * 2 * NBINS;
    unsigned* posnh = hist + (size_t)Bdim * Kdim * 2 * NBINS;
    int tid = blockIdx.x * blockDim.x + threadIdx.x;
    const float* bp = yp + (size_t)b * 5 * HWPIX;
    const int* bt = yt + (size_t)b * HWPIX;

    float ssum = 0.f;
    for (int p = 0; p < PPT; ++p) {
        int hw = tid + p * PSTRIDE;
        float offy = bp[hw];
        float offx = bp[hw + HWPIX];
        float sy = bp[hw + 2 * HWPIX];
        float sx = bp[hw + 3 * HWPIX];
        float seed = bp[hw + 4 * HWPIX];
        int own = bt[hw] - 1;  // -1..15
        int h = hw / Wdim;
        int w = hw - h * Wdim;
        float ey = (float)h + offy, ex = (float)w + offx;
        float sby = fmaxf(sy, EPSf), sbx = fmaxf(sx, EPSf);
        float iy = 0.5f / (sby * sby), ix = 0.5f / (sbx * sbx);

        // fast pass: flag the rare (k) with q < QCLIP
        unsigned sm = 0;
#pragma unroll
        for (int k = 0; k < Kdim; ++k) {
            float dy = ey - cky[k];
            float dx = ex - ckx[k];
            float q = fmaf(dy * dy, iy, dx * dx * ix);
            if (q < QCLIP) sm |= (1u << k);
        }
        float st = (own >= 0) ? EPSf : 0.f;  // clamped-phi seed target by default
        // slow path: near some center (rare, divergent)
        while (sm) {
            int k = __ffs(sm) - 1;
            sm &= sm - 1;
            float dy = ey - ck_s[k * 2];
            float dx = ex - ck_s[k * 2 + 1];
            float q = fmaf(dy * dy, iy, dx * dx * ix);
            float phi = expf(-q);
            phi = fminf(fmaxf(phi, EPSf), 1.0f - EPSf);
            float lg = logf(phi) - log1pf(-phi);
            bool isPos = (k == own);
            float e;
            if (isPos) {
                st = phi;
                atomicAdd(&posnh[b * Kdim + k], 1u);  // not an implicit-hot positive
                e = 1.0f - lg;
            } else {
                e = 1.0f + lg;
            }
            if (e > 0.f) {
                int bin = (int)(e * INV_BIN_W);
                if (bin > NBINS - 1) bin = NBINS - 1;
                atomicAdd(&hb[(k * 2 + (isPos ? 1 : 0)) * NBINS + bin], 1u);
            }
        }
        if (own >= 0) {
            float devv = fabsf(sy - ms_s[own * 2]) + fabsf(sx - ms_s[own * 2 + 1]);
            atomicAdd(&devs[own], devv);
        }
        float dd = seed - st;
        ssum += dd * dd;
    }
    // wave reduce seed, then one block atomic
    for (int o = 32; o >= 1; o >>= 1) ssum += __shfl_down(ssum, o);
    if (lane == 0) atomicAdd(&seed_s, ssum);
    __syncthreads();
    if (threadIdx.x == 0) atomicAdd(&ws[SEED_OFF], seed_s);
    if (threadIdx.x < 16) {
        float v = devs[threadIdx.x];
        if (v != 0.f) atomicAdd(&ws[DEV_OFF + b * Kdim + threadIdx.x], v);
    }
}

// One wave per (b,k): suffix-scan histogram top-down, trapezoid-integrate
// J(t) = 1 - (P - p(t))/(P + n(t)).  Clamped positives enter implicitly as
// deficit = P - posnh at HOTBIN.
__global__ void k_lovasz(float* __restrict__ ws, const unsigned* __restrict__ hist) {
    int i = blockIdx.x;  // 0..63
    int lane = threadIdx.x;
    float P = ws[ACC_OFF + i * 5];
    if (P < 0.5f) return;
    const unsigned* hn = hist + (size_t)i * 2 * NBINS;
    const unsigned* hp = hn + NBINS;
    const unsigned* posnh = hist + (size_t)Bdim * Kdim * 2 * NBINS;
    const float C_LO = logf(EPSf) - log1pf(-EPSf);
    const int HOTBIN = (int)((1.0f - C_LO) * INV_BIN_W);
    int deficit = (int)(P + 0.5f) - (int)posnh[i];
    int carry_p = 0, carry_n = 0;
    float Jtop = 0.f;
    float trap = 0.f;
    for (int c = NBINS / 64 - 1; c >= 0; --c) {
        int m = c * 64 + lane;
        int vp = (int)hp[m];
        int vn = (int)hn[m];
        if (m == HOTBIN) vp += deficit;
        for (int o = 1; o < 64; o <<= 1) {
            int tp = __shfl_down(vp, o);
            int tn = __shfl_down(vn, o);
            if (lane + o < 64) { vp += tp; vn += tn; }
        }
        float p_edge = (float)(carry_p + vp);
        float n_edge = (float)(carry_n + vn);
        float J = 1.0f - (P - p_edge) / (P + n_edge);
        float Jn = __shfl_down(J, 1);
        if (lane == 63) Jn = Jtop;
        trap += 0.5f * (J + Jn);
        carry_p += __shfl(vp, 0);
        carry_n += __shfl(vn, 0);
        Jtop = __shfl(J, 0);
    }
    for (int o = 1; o < 64; o <<= 1) {
        float t2 = __shfl_down(trap, o);
        if (lane + o < 64) trap += t2;
    }
    if (lane == 0) atomicAdd(&ws[LOV_OFF], trap * BIN_W);
}

__global__ void k_final(const float* __restrict__ ws, float* __restrict__ out) {
    float npres = ws[NPRES_OFF];
    float L_iou = ws[LOV_OFF] / npres;
    float lv = 0.f;
    for (int i = 0; i < Bdim * Kdim; ++i) {
        float cnt = ws[ACC_OFF + i * 5];
        if (cnt > 0.f) lv += ws[DEV_OFF + i] / (2.0f * cnt);
    }
    float L_var = lv / npres;
    float L_seed = ws[SEED_OFF] / (float)((size_t)Bdim * HWPIX);
    out[0] = L_iou + 10.0f * L_var + L_seed;
}

extern "C" void kernel_launch(void* const* d_in, const int* in_sizes, int n_in,
                              void* d_out, int out_size, void* d_ws, size_t ws_size,
                              hipStream_t stream) {
    const float* yp = (const float*)d_in[0];
    const int* yt = (const int*)d_in[1];
    float* ws = (float*)d_ws;
    unsigned* hist = (unsigned*)((char*)d_ws + HIST_OFF_F * 4);

    hipMemsetAsync(d_ws, 0, WS_ZERO_BYTES, stream);

    dim3 g(SBLK, Bdim);
    k_stats<<<g, 256, 0, stream>>>(yp, yt, ws);
    k_centers<<<1, 64, 0, stream>>>(ws);
    k_main<<<g, 256, 0, stream>>>(yp, yt, ws, hist);
    k_lovasz<<<64, 64, 0, stream>>>(ws, hist);
    k_final<<<1, 1, 0, stream>>>(ws, (float*)d_out);
}

// Round 3
// 124.969 us; speedup vs baseline: 3.7056x; 1.1263x over previous
//
#include <hip/hip_runtime.h>

#define HWPIX 589824
#define Hdim 768
#define Wdim 768
#define Bdim 4
#define Kdim 16
#define NBINS 2048
#define RANGE_F 16.0f
#define BIN_W (RANGE_F / NBINS)
#define INV_BIN_W (NBINS / RANGE_F)
#define EPSf 1e-6f
#define QCLIP 13.8155106f   /* -log(1e-6): q >= QCLIP  <=>  phi clamps to EPS */

// grid geometry
#define NSB 192                       // blocks per batch
#define PPT 12                        // pixels per thread: 192*256*12 = 589824
#define PSTRIDE (NSB * 256)

// ws float offsets
#define ACC_OFF 0                     // [B][K][5]: count, s_emb_y, s_emb_x, s_sig_y, s_sig_x
#define CK_OFF 320                    // [B][K][2]
#define MS_OFF 448                    // [B][K][2]
#define PRES_OFF 576                  // [B][K]
#define NPRES_OFF 640
#define LOVARR_OFF 644                // [B*K]
#define HIST_OFF_F 768                // uint hist[B*K][2][NBINS]
#define NHIST (Bdim * Kdim * 2 * NBINS)          // 262144
#define POSNH_OFF_F (HIST_OFF_F + NHIST)         // uint [B*K]
#define SPART_OFF (POSNH_OFF_F + 64)             // float [B*NSB][80]
#define SPART_SZ (Bdim * NSB * 80)
#define MPART_OFF (SPART_OFF + SPART_SZ)         // float [B*NSB][17]
#define MPART_SZ (Bdim * NSB * 17)

__global__ void k_stats(const float* __restrict__ yp, const int* __restrict__ yt,
                        float* __restrict__ ws) {
    int b = blockIdx.y;
    int set = threadIdx.x >> 4;       // 16 sets of 16 lanes
    __shared__ float lacc[16 * 81];   // stride 81: sets spread across all banks
    for (int i = threadIdx.x; i < 16 * 81; i += blockDim.x) lacc[i] = 0.f;
    __syncthreads();
    int tid = blockIdx.x * blockDim.x + threadIdx.x;
    const float* bp = yp + (size_t)b * 5 * HWPIX;
    const int* bt = yt + (size_t)b * HWPIX;
    for (int p = 0; p < PPT; ++p) {
        int hw = tid + p * PSTRIDE;
        // unconditional loads: no dependent branch, all 5 streams pipeline
        float offy = bp[hw];
        float offx = bp[hw + HWPIX];
        float sy = bp[hw + 2 * HWPIX];
        float sx = bp[hw + 3 * HWPIX];
        int t = bt[hw];
        if (t >= 1 && t <= Kdim) {
            int k = t - 1;
            int h = hw / Wdim;
            int w = hw - h * Wdim;
            float* a = &lacc[set * 81 + k * 5];
            atomicAdd(a + 0, 1.0f);
            atomicAdd(a + 1, (float)h + offy);
            atomicAdd(a + 2, (float)w + offx);
            atomicAdd(a + 3, sy);
            atomicAdd(a + 4, sx);
        }
    }
    __syncthreads();
    if (threadIdx.x < 80) {
        float v = 0.f;
#pragma unroll
        for (int s = 0; s < 16; ++s) v += lacc[s * 81 + threadIdx.x];
        ws[SPART_OFF + (size_t)(b * NSB + blockIdx.x) * 80 + threadIdx.x] = v;
    }
}

// stage B: reduce stats partials, compute centers/means/presence
__global__ void k_centers(float* __restrict__ ws) {
    int t = threadIdx.x;  // 0..319
    if (t < 320) {
        int b = t / 80, idx = t - b * 80;
        float s = 0.f;
        const float* sp = ws + SPART_OFF + (size_t)b * NSB * 80 + idx;
        for (int j = 0; j < NSB; ++j) s += sp[(size_t)j * 80];
        ws[ACC_OFF + b * 80 + idx] = s;
    }
    __syncthreads();
    if (t < 64) {
        float cnt = ws[ACC_OFF + t * 5];
        float safe = fmaxf(cnt, 1.0f);
        ws[CK_OFF + t * 2 + 0] = ws[ACC_OFF + t * 5 + 1] / safe;
        ws[CK_OFF + t * 2 + 1] = ws[ACC_OFF + t * 5 + 2] / safe;
        ws[MS_OFF + t * 2 + 0] = ws[ACC_OFF + t * 5 + 3] / safe;
        ws[MS_OFF + t * 2 + 1] = ws[ACC_OFF + t * 5 + 4] / safe;
        ws[PRES_OFF + t] = (cnt > 0.f) ? 1.f : 0.f;
    }
    __syncthreads();
    if (t == 0) {
        float s = 0.f;
        for (int j = 0; j < Bdim * Kdim; ++j) s += ws[PRES_OFF + j];
        ws[NPRES_OFF] = fmaxf(s, 1.0f);
    }
}

__global__ void k_main(const float* __restrict__ yp, const int* __restrict__ yt,
                       float* __restrict__ ws, unsigned* __restrict__ hist) {
    int b = blockIdx.y;
    int lane = threadIdx.x & 63;
    int wv = threadIdx.x >> 6;
    __shared__ float ck_s[32], ms_s[32];
    __shared__ float devs[4][17];
    __shared__ float swave[4];
    if (threadIdx.x < 32) {
        ck_s[threadIdx.x] = ws[CK_OFF + b * 32 + threadIdx.x];
        ms_s[threadIdx.x] = ws[MS_OFF + b * 32 + threadIdx.x];
    }
    if (threadIdx.x < 4 * 17) ((float*)devs)[threadIdx.x] = 0.f;
    __syncthreads();

    float cky[Kdim], ckx[Kdim];
#pragma unroll
    for (int k = 0; k < Kdim; ++k) {
        cky[k] = ck_s[k * 2];
        ckx[k] = ck_s[k * 2 + 1];
    }

    unsigned* hb = hist + (size_t)(b * Kdim) * 2 * NBINS;
    unsigned* posnh = hist + (size_t)NHIST;
    int tid = blockIdx.x * blockDim.x + threadIdx.x;
    const float* bp = yp + (size_t)b * 5 * HWPIX;
    const int* bt = yt + (size_t)b * HWPIX;

    float ssum = 0.f;
    for (int p = 0; p < PPT; ++p) {
        int hw = tid + p * PSTRIDE;
        float offy = bp[hw];
        float offx = bp[hw + HWPIX];
        float sy = bp[hw + 2 * HWPIX];
        float sx = bp[hw + 3 * HWPIX];
        float seed = bp[hw + 4 * HWPIX];
        int own = bt[hw] - 1;  // -1..15
        int h = hw / Wdim;
        int w = hw - h * Wdim;
        float ey = (float)h + offy, ex = (float)w + offx;
        float sby = fmaxf(sy, EPSf), sbx = fmaxf(sx, EPSf);
        float iy = 0.5f / (sby * sby), ix = 0.5f / (sbx * sbx);

        unsigned sm = 0;
#pragma unroll
        for (int k = 0; k < Kdim; ++k) {
            float dy = ey - cky[k];
            float dx = ex - ckx[k];
            float q = fmaf(dy * dy, iy, dx * dx * ix);
            if (q < QCLIP) sm |= (1u << k);
        }
        float st = (own >= 0) ? EPSf : 0.f;  // clamped-phi seed target by default
        while (sm) {  // rare slow path
            int k = __ffs(sm) - 1;
            sm &= sm - 1;
            float dy = ey - ck_s[k * 2];
            float dx = ex - ck_s[k * 2 + 1];
            float q = fmaf(dy * dy, iy, dx * dx * ix);
            float phi = expf(-q);
            phi = fminf(fmaxf(phi, EPSf), 1.0f - EPSf);
            float lg = logf(phi) - log1pf(-phi);
            bool isPos = (k == own);
            float e;
            if (isPos) {
                st = phi;
                atomicAdd(&posnh[b * Kdim + k], 1u);
                e = 1.0f - lg;
            } else {
                e = 1.0f + lg;
            }
            if (e > 0.f) {
                int bin = (int)(e * INV_BIN_W);
                if (bin > NBINS - 1) bin = NBINS - 1;
                atomicAdd(&hb[(k * 2 + (isPos ? 1 : 0)) * NBINS + bin], 1u);
            }
        }
        if (own >= 0) {
            float devv = fabsf(sy - ms_s[own * 2]) + fabsf(sx - ms_s[own * 2 + 1]);
            atomicAdd(&devs[wv][own], devv);
        }
        float dd = seed - st;
        ssum += dd * dd;
    }
    for (int o = 32; o >= 1; o >>= 1) ssum += __shfl_down(ssum, o);
    if (lane == 0) swave[wv] = ssum;
    __syncthreads();
    float* mp = ws + MPART_OFF + (size_t)(b * NSB + blockIdx.x) * 17;
    if (threadIdx.x < 16)
        mp[threadIdx.x] = devs[0][threadIdx.x] + devs[1][threadIdx.x] +
                          devs[2][threadIdx.x] + devs[3][threadIdx.x];
    if (threadIdx.x == 16) mp[16] = swave[0] + swave[1] + swave[2] + swave[3];
}

// One wave per (b,k): suffix-scan histogram top-down, trapezoid-integrate
// J(t) = 1 - (P - p(t))/(P + n(t)).  Clamped positives enter implicitly as
// deficit = P - posnh at HOTBIN.
__global__ void k_lovasz(float* __restrict__ ws, const unsigned* __restrict__ hist) {
    int i = blockIdx.x;  // 0..63
    int lane = threadIdx.x;
    float P = ws[ACC_OFF + i * 5];
    if (P < 0.5f) {
        if (lane == 0) ws[LOVARR_OFF + i] = 0.f;
        return;
    }
    const unsigned* hn = hist + (size_t)i * 2 * NBINS;
    const unsigned* hp = hn + NBINS;
    const unsigned* posnh = hist + (size_t)NHIST;
    const float C_LO = logf(EPSf) - log1pf(-EPSf);
    const int HOTBIN = (int)((1.0f - C_LO) * INV_BIN_W);
    int deficit = (int)(P + 0.5f) - (int)posnh[i];
    int carry_p = 0, carry_n = 0;
    float Jtop = 0.f;
    float trap = 0.f;
    for (int c = NBINS / 64 - 1; c >= 0; --c) {
        int m = c * 64 + lane;
        int vp = (int)hp[m];
        int vn = (int)hn[m];
        if (m == HOTBIN) vp += deficit;
        for (int o = 1; o < 64; o <<= 1) {
            int tp = __shfl_down(vp, o);
            int tn = __shfl_down(vn, o);
            if (lane + o < 64) { vp += tp; vn += tn; }
        }
        float p_edge = (float)(carry_p + vp);
        float n_edge = (float)(carry_n + vn);
        float J = 1.0f - (P - p_edge) / (P + n_edge);
        float Jn = __shfl_down(J, 1);
        if (lane == 63) Jn = Jtop;
        trap += 0.5f * (J + Jn);
        carry_p += __shfl(vp, 0);
        carry_n += __shfl(vn, 0);
        Jtop = __shfl(J, 0);
    }
    for (int o = 1; o < 64; o <<= 1) {
        float t2 = __shfl_down(trap, o);
        if (lane + o < 64) trap += t2;
    }
    if (lane == 0) ws[LOVARR_OFF + i] = trap * BIN_W;
}

__global__ void k_final(const float* __restrict__ ws, float* __restrict__ out) {
    __shared__ float ssum[256];
    int t = threadIdx.x;
    const float* mp = ws + MPART_OFF;
    // seed: sum mpart[j][16] over all 768 blocks
    float se = 0.f;
    for (int j = t; j < Bdim * NSB; j += 256) se += mp[(size_t)j * 17 + 16];
    ssum[t] = se;
    __syncthreads();
    for (int s2 = 128; s2 > 0; s2 >>= 1) {
        if (t < s2) ssum[t] += ssum[t + s2];
        __syncthreads();
    }
    // per-(b,k): dev sum over 192 partials, plus lovasz, on first wave
    float var_c = 0.f, lov_c = 0.f;
    if (t < 64) {
        int b = t >> 4, k = t & 15;
        float dv = 0.f;
        const float* mb = mp + (size_t)b * NSB * 17 + k;
        for (int j = 0; j < NSB; ++j) dv += mb[(size_t)j * 17];
        float cnt = ws[ACC_OFF + t * 5];
        var_c = (cnt > 0.f) ? dv / (2.0f * cnt) : 0.f;
        lov_c = ws[LOVARR_OFF + t];
    }
    if (t < 64) {
        for (int o = 32; o >= 1; o >>= 1) {
            var_c += __shfl_down(var_c, o);
            lov_c += __shfl_down(lov_c, o);
        }
    }
    if (t == 0) {
        float npres = ws[NPRES_OFF];
        float L_iou = lov_c / npres;
        float L_var = var_c / npres;
        float L_seed = ssum[0] / (float)((size_t)Bdim * HWPIX);
        out[0] = L_iou + 10.0f * L_var + L_seed;
    }
}

extern "C" void kernel_launch(void* const* d_in, const int* in_sizes, int n_in,
                              void* d_out, int out_size, void* d_ws, size_t ws_size,
                              hipStream_t stream) {
    const float* yp = (const float*)d_in[0];
    const int* yt = (const int*)d_in[1];
    float* ws = (float*)d_ws;
    unsigned* hist = (unsigned*)((char*)d_ws + HIST_OFF_F * 4);

    // zero only hist + posnh (everything else is plain-stored each call)
    hipMemsetAsync((char*)d_ws + HIST_OFF_F * 4, 0, (size_t)(NHIST + 64) * 4, stream);

    dim3 g(NSB, Bdim);
    k_stats<<<g, 256, 0, stream>>>(yp, yt, ws);
    k_centers<<<1, 320, 0, stream>>>(ws);
    k_main<<<g, 256, 0, stream>>>(yp, yt, ws, hist);
    k_lovasz<<<64, 64, 0, stream>>>(ws, hist);
    k_final<<<1, 256, 0, stream>>>(ws, (float*)d_out);
}

// Round 4
// 93.387 us; speedup vs baseline: 4.9588x; 1.3382x over previous
//
#include <hip/hip_runtime.h>

#define HWPIX 589824
#define Wdim 768
#define Bdim 4
#define Kdim 16
#define NBINS 2048
#define RANGE_F 16.0f
#define BIN_W (RANGE_F / NBINS)
#define INV_BIN_W (NBINS / RANGE_F)
#define EPSf 1e-6f
#define QCLIP 13.8155106f   /* -log(1e-6): q >= QCLIP  <=>  phi clamps to EPS */

#define NSB 192                        // blocks per batch
#define Q4 (HWPIX / 4)                 // 147456 float4 groups per channel
#define GPI (NSB * 256)                // groups per iteration = 49152

// ws float offsets
#define ACC_OFF 0                      // [B][K][5]
#define CK_OFF 320                     // [B][K][2]
#define MSW_OFF 448                    // float4 [B][17]: ms_y, ms_x, w, 0
#define NPRES_OFF 720
#define LOVARR_OFF 724                 // [64]
#define HIST_OFF_F 1024                // uint hist[B*K][2][NBINS]
#define NHIST (Bdim * Kdim * 2 * NBINS)
#define POSNH_OFF_F (HIST_OFF_F + NHIST)
#define SPART_OFF (POSNH_OFF_F + 64)   // float [B*NSB][80]
#define MPART_OFF (SPART_OFF + Bdim * NSB * 80)  // float [B*NSB][2]

__global__ __launch_bounds__(256, 3) void k_stats(const float* __restrict__ yp,
                                                  const int* __restrict__ yt,
                                                  float* __restrict__ ws) {
    int b = blockIdx.y;
    int lane = threadIdx.x & 63;
    int wv = threadIdx.x >> 6;
    __shared__ float lpart[4][80];
    const float4* bp4 = (const float4*)(yp + (size_t)b * 5 * HWPIX);
    const int4* bt4 = (const int4*)(yt + (size_t)b * HWPIX);

    float acc[80];
#pragma unroll
    for (int v = 0; v < 80; ++v) acc[v] = 0.f;

    for (int p = 0; p < 3; ++p) {
        int g = p * GPI + blockIdx.x * 256 + threadIdx.x;
        float4 voy = bp4[g];
        float4 vox = bp4[g + Q4];
        float4 vsy = bp4[g + 2 * Q4];
        float4 vsx = bp4[g + 3 * Q4];
        int4 vt = bt4[g];
        int hwb = g * 4;
        float oy[4] = {voy.x, voy.y, voy.z, voy.w};
        float ox[4] = {vox.x, vox.y, vox.z, vox.w};
        float sy[4] = {vsy.x, vsy.y, vsy.z, vsy.w};
        float sx[4] = {vsx.x, vsx.y, vsx.z, vsx.w};
        int tt[4] = {vt.x, vt.y, vt.z, vt.w};
#pragma unroll
        for (int j = 0; j < 4; ++j) {
            int hw = hwb + j;
            int h = hw / Wdim;
            int w = hw - h * Wdim;
            int own = tt[j] - 1;
            float vy = (float)h + oy[j];
            float vx = (float)w + ox[j];
#pragma unroll
            for (int k = 0; k < Kdim; ++k) {
                float m = (own == k) ? 1.0f : 0.0f;
                acc[k * 5 + 0] += m;
                acc[k * 5 + 1] = fmaf(m, vy, acc[k * 5 + 1]);
                acc[k * 5 + 2] = fmaf(m, vx, acc[k * 5 + 2]);
                acc[k * 5 + 3] = fmaf(m, sy[j], acc[k * 5 + 3]);
                acc[k * 5 + 4] = fmaf(m, sx[j], acc[k * 5 + 4]);
            }
        }
    }

    // fold across half-waves: lanes 0-31 own values 0..39, lanes 32-63 own 40..79
    bool lo = (lane < 32);
#pragma unroll
    for (int v = 0; v < 40; ++v) {
        float send = lo ? acc[v + 40] : acc[v];
        float got = __shfl_xor(send, 32);
        acc[v] += lo ? got : 0.f;
        acc[v + 40] += lo ? 0.f : got;
    }
#pragma unroll
    for (int v = 0; v < 40; ++v) {
        float x = lo ? acc[v] : acc[v + 40];
#pragma unroll
        for (int o = 16; o >= 1; o >>= 1) x += __shfl_xor(x, o);
        if ((lane & 31) == 0) lpart[wv][lo ? v : v + 40] = x;
    }
    __syncthreads();
    if (threadIdx.x < 80) {
        float v = lpart[0][threadIdx.x] + lpart[1][threadIdx.x] +
                  lpart[2][threadIdx.x] + lpart[3][threadIdx.x];
        ws[SPART_OFF + (size_t)(b * NSB + blockIdx.x) * 80 + threadIdx.x] = v;
    }
}

__global__ void k_centers(float* __restrict__ ws) {
    int t = threadIdx.x;  // 320 threads
    int b = t / 80, idx = t - b * 80;
    float s = 0.f;
    const float* sp = ws + SPART_OFF + (size_t)b * NSB * 80 + idx;
    for (int j = 0; j < NSB; ++j) s += sp[j * 80];
    ws[ACC_OFF + t] = s;
    __syncthreads();
    if (t < 64) {
        float cnt = ws[ACC_OFF + t * 5];
        float safe = fmaxf(cnt, 1.0f);
        ws[CK_OFF + t * 2 + 0] = ws[ACC_OFF + t * 5 + 1] / safe;
        ws[CK_OFF + t * 2 + 1] = ws[ACC_OFF + t * 5 + 2] / safe;
        int bb = t >> 4, kk = t & 15;
        float* mw = ws + MSW_OFF + (size_t)(bb * 17 + kk) * 4;
        mw[0] = ws[ACC_OFF + t * 5 + 3] / safe;
        mw[1] = ws[ACC_OFF + t * 5 + 4] / safe;
        mw[2] = (cnt > 0.f) ? 0.5f / cnt : 0.f;
        mw[3] = 0.f;
    }
    if (t >= 64 && t < 68) {
        float* mw = ws + MSW_OFF + (size_t)((t - 64) * 17 + 16) * 4;
        mw[0] = mw[1] = mw[2] = mw[3] = 0.f;
    }
    __syncthreads();
    if (t == 0) {
        float s2 = 0.f;
        for (int j = 0; j < 64; ++j) s2 += (ws[ACC_OFF + j * 5] > 0.f) ? 1.f : 0.f;
        ws[NPRES_OFF] = fmaxf(s2, 1.0f);
    }
}

__global__ __launch_bounds__(256, 3) void k_main(const float* __restrict__ yp,
                                                 const int* __restrict__ yt,
                                                 float* __restrict__ ws,
                                                 unsigned* __restrict__ hist) {
    int b = blockIdx.y;
    int lane = threadIdx.x & 63;
    int wv = threadIdx.x >> 6;
    __shared__ float ck_s[32];
    __shared__ float4 msw_s[17];
    __shared__ float part[4][2];
    if (threadIdx.x < 32) ck_s[threadIdx.x] = ws[CK_OFF + b * 32 + threadIdx.x];
    if (threadIdx.x < 17)
        msw_s[threadIdx.x] = ((const float4*)(ws + MSW_OFF))[b * 17 + threadIdx.x];
    __syncthreads();

    float cky[Kdim], ckx[Kdim];
#pragma unroll
    for (int k = 0; k < Kdim; ++k) {
        cky[k] = ck_s[k * 2];
        ckx[k] = ck_s[k * 2 + 1];
    }

    unsigned* hb = hist + (size_t)(b * Kdim) * 2 * NBINS;
    unsigned* posnh = hist + (size_t)NHIST;
    const float4* bp4 = (const float4*)(yp + (size_t)b * 5 * HWPIX);
    const int4* bt4 = (const int4*)(yt + (size_t)b * HWPIX);

    float varsum = 0.f, ssum = 0.f;
    for (int p = 0; p < 3; ++p) {
        int g = p * GPI + blockIdx.x * 256 + threadIdx.x;
        float4 voy = bp4[g];
        float4 vox = bp4[g + Q4];
        float4 vsy = bp4[g + 2 * Q4];
        float4 vsx = bp4[g + 3 * Q4];
        float4 vse = bp4[g + 4 * Q4];
        int4 vt = bt4[g];
        int hwb = g * 4;
        float oy[4] = {voy.x, voy.y, voy.z, voy.w};
        float ox[4] = {vox.x, vox.y, vox.z, vox.w};
        float sya[4] = {vsy.x, vsy.y, vsy.z, vsy.w};
        float sxa[4] = {vsx.x, vsx.y, vsx.z, vsx.w};
        float sea[4] = {vse.x, vse.y, vse.z, vse.w};
        int tt[4] = {vt.x, vt.y, vt.z, vt.w};
#pragma unroll
        for (int j = 0; j < 4; ++j) {
            int hw = hwb + j;
            int h = hw / Wdim;
            int w = hw - h * Wdim;
            int own = tt[j] - 1;
            float sy = sya[j], sx = sxa[j];
            float ey = (float)h + oy[j], ex = (float)w + ox[j];
            float sby = fmaxf(sy, EPSf), sbx = fmaxf(sx, EPSf);
            float iy = 0.5f / (sby * sby), ix = 0.5f / (sbx * sbx);

            unsigned sm = 0;
#pragma unroll
            for (int k = 0; k < Kdim; ++k) {
                float dy = ey - cky[k];
                float dx = ex - ckx[k];
                float q = fmaf(dy * dy, iy, dx * dx * ix);
                if (q < QCLIP) sm |= (1u << k);
            }
            // dev + var contribution (slot 16 = zeros for unlabeled)
            int ow = (own >= 0) ? own : 16;
            float4 mw = msw_s[ow];
            float devv = fabsf(sy - mw.x) + fabsf(sx - mw.y);
            varsum = fmaf(devv, mw.z, varsum);

            float st = (own >= 0) ? EPSf : 0.f;
            while (sm) {  // rare slow path
                int k = __ffs(sm) - 1;
                sm &= sm - 1;
                float dy = ey - ck_s[k * 2];
                float dx = ex - ck_s[k * 2 + 1];
                float q = fmaf(dy * dy, iy, dx * dx * ix);
                float phi = expf(-q);
                phi = fminf(fmaxf(phi, EPSf), 1.0f - EPSf);
                float lg = logf(phi) - log1pf(-phi);
                bool isPos = (k == own);
                float e;
                if (isPos) {
                    st = phi;
                    atomicAdd(&posnh[b * Kdim + k], 1u);
                    e = 1.0f - lg;
                } else {
                    e = 1.0f + lg;
                }
                if (e > 0.f) {
                    int bin = (int)(e * INV_BIN_W);
                    if (bin > NBINS - 1) bin = NBINS - 1;
                    atomicAdd(&hb[(k * 2 + (isPos ? 1 : 0)) * NBINS + bin], 1u);
                }
            }
            float dd = sea[j] - st;
            ssum = fmaf(dd, dd, ssum);
        }
    }
#pragma unroll
    for (int o = 32; o >= 1; o >>= 1) {
        varsum += __shfl_xor(varsum, o);
        ssum += __shfl_xor(ssum, o);
    }
    if (lane == 0) {
        part[wv][0] = varsum;
        part[wv][1] = ssum;
    }
    __syncthreads();
    if (threadIdx.x < 2) {
        float v = part[0][threadIdx.x] + part[1][threadIdx.x] +
                  part[2][threadIdx.x] + part[3][threadIdx.x];
        ws[MPART_OFF + (size_t)(b * NSB + blockIdx.x) * 2 + threadIdx.x] = v;
    }
}

__global__ void k_lovasz(float* __restrict__ ws, const unsigned* __restrict__ hist) {
    int i = blockIdx.x;  // 0..63
    int lane = threadIdx.x;
    float P = ws[ACC_OFF + i * 5];
    if (P < 0.5f) {
        if (lane == 0) ws[LOVARR_OFF + i] = 0.f;
        return;
    }
    const unsigned* hn = hist + (size_t)i * 2 * NBINS;
    const unsigned* hp = hn + NBINS;
    const unsigned* posnh = hist + (size_t)NHIST;
    const float C_LO = logf(EPSf) - log1pf(-EPSf);
    const int HOTBIN = (int)((1.0f - C_LO) * INV_BIN_W);
    int deficit = (int)(P + 0.5f) - (int)posnh[i];
    int carry_p = 0, carry_n = 0;
    float Jtop = 0.f;
    float trap = 0.f;
    for (int c = NBINS / 64 - 1; c >= 0; --c) {
        int m = c * 64 + lane;
        int vp = (int)hp[m];
        int vn = (int)hn[m];
        if (m == HOTBIN) vp += deficit;
        for (int o = 1; o < 64; o <<= 1) {
            int tp = __shfl_down(vp, o);
            int tn = __shfl_down(vn, o);
            if (lane + o < 64) { vp += tp; vn += tn; }
        }
        float p_edge = (float)(carry_p + vp);
        float n_edge = (float)(carry_n + vn);
        float J = 1.0f - (P - p_edge) / (P + n_edge);
        float Jn = __shfl_down(J, 1);
        if (lane == 63) Jn = Jtop;
        trap += 0.5f * (J + Jn);
        carry_p += __shfl(vp, 0);
        carry_n += __shfl(vn, 0);
        Jtop = __shfl(J, 0);
    }
    for (int o = 1; o < 64; o <<= 1) {
        float t2 = __shfl_down(trap, o);
        if (lane + o < 64) trap += t2;
    }
    if (lane == 0) ws[LOVARR_OFF + i] = trap * BIN_W;
}

__global__ void k_final(const float* __restrict__ ws, float* __restrict__ out) {
    __shared__ float r0[256], r1[256], r2[256];
    int t = threadIdx.x;
    float v = 0.f, s = 0.f, l = 0.f;
    for (int j = t; j < Bdim * NSB; j += 256) {
        v += ws[MPART_OFF + 2 * j];
        s += ws[MPART_OFF + 2 * j + 1];
    }
    if (t < 64) l = ws[LOVARR_OFF + t];
    r0[t] = v; r1[t] = s; r2[t] = l;
    __syncthreads();
    for (int o = 128; o > 0; o >>= 1) {
        if (t < o) { r0[t] += r0[t + o]; r1[t] += r1[t + o]; r2[t] += r2[t + o]; }
        __syncthreads();
    }
    if (t == 0) {
        float npres = ws[NPRES_OFF];
        out[0] = r2[0] / npres + 10.0f * (r0[0] / npres) +
                 r1[0] / (float)((size_t)Bdim * HWPIX);
    }
}

extern "C" void kernel_launch(void* const* d_in, const int* in_sizes, int n_in,
                              void* d_out, int out_size, void* d_ws, size_t ws_size,
                              hipStream_t stream) {
    const float* yp = (const float*)d_in[0];
    const int* yt = (const int*)d_in[1];
    float* ws = (float*)d_ws;
    unsigned* hist = (unsigned*)((char*)d_ws + HIST_OFF_F * 4);

    hipMemsetAsync((char*)d_ws + HIST_OFF_F * 4, 0, (size_t)(NHIST + 64) * 4, stream);

    dim3 g(NSB, Bdim);
    k_stats<<<g, 256, 0, stream>>>(yp, yt, ws);
    k_centers<<<1, 320, 0, stream>>>(ws);
    k_main<<<g, 256, 0, stream>>>(yp, yt, ws, hist);
    k_lovasz<<<64, 64, 0, stream>>>(ws, hist);
    k_final<<<1, 256, 0, stream>>>(ws, (float*)d_out);
}

// Round 5
// 87.154 us; speedup vs baseline: 5.3134x; 1.0715x over previous
//
#include <hip/hip_runtime.h>

#define HWPIX 589824
#define Wdim 768
#define Bdim 4
#define Kdim 16
#define NBINS 2048
#define RANGE_F 16.0f
#define BIN_W (RANGE_F / NBINS)
#define INV_BIN_W (NBINS / RANGE_F)
#define EPSf 1e-6f
#define QCLIP 13.8155106f   /* -log(1e-6): q >= QCLIP  <=>  phi clamps to EPS */

#define NSB 192                        // blocks per batch
#define Q4 (HWPIX / 4)                 // 147456 float4 groups per channel
#define GPI (NSB * 256)                // groups per iteration = 49152
#define NTHREADS_TOT (NSB * Bdim * 256)

// ws float offsets
#define ACC_OFF 0                      // [B][K][5]
#define CK_OFF 320                     // [B][K][2]
#define MSW_OFF 448                    // float4 [B][17]: ms_y, ms_x, w, 0
#define NPRES_OFF 720
#define LOVARR_OFF 724                 // [64]
#define HIST_OFF_F 1024                // uint hist[B*K][2][NBINS]
#define NHIST (Bdim * Kdim * 2 * NBINS)
#define POSNH_OFF_F (HIST_OFF_F + NHIST)
#define SPART_OFF (POSNH_OFF_F + 64)   // float [B*NSB][80]
#define MPART_OFF (SPART_OFF + Bdim * NSB * 80)  // float [B*NSB][2]

__global__ __launch_bounds__(256, 3) void k_stats(const float* __restrict__ yp,
                                                  const int* __restrict__ yt,
                                                  float* __restrict__ ws,
                                                  unsigned* __restrict__ hist) {
    int b = blockIdx.y;
    int lane = threadIdx.x & 63;
    int wv = threadIdx.x >> 6;
    __shared__ float lpart[4][80];

    // zero hist + posnh (replaces the 40us hipMemsetAsync dispatch)
    {
        int gtid = (blockIdx.y * NSB + blockIdx.x) * 256 + threadIdx.x;
        for (int i = gtid; i < NHIST + 64; i += NTHREADS_TOT) hist[i] = 0u;
    }

    const float4* bp4 = (const float4*)(yp + (size_t)b * 5 * HWPIX);
    const int4* bt4 = (const int4*)(yt + (size_t)b * HWPIX);

    float acc[80];
#pragma unroll
    for (int v = 0; v < 80; ++v) acc[v] = 0.f;

    for (int p = 0; p < 3; ++p) {
        int g = p * GPI + blockIdx.x * 256 + threadIdx.x;
        float4 voy = bp4[g];
        float4 vox = bp4[g + Q4];
        float4 vsy = bp4[g + 2 * Q4];
        float4 vsx = bp4[g + 3 * Q4];
        int4 vt = bt4[g];
        int hwb = g * 4;
        float oy[4] = {voy.x, voy.y, voy.z, voy.w};
        float ox[4] = {vox.x, vox.y, vox.z, vox.w};
        float sy[4] = {vsy.x, vsy.y, vsy.z, vsy.w};
        float sx[4] = {vsx.x, vsx.y, vsx.z, vsx.w};
        int tt[4] = {vt.x, vt.y, vt.z, vt.w};
#pragma unroll
        for (int j = 0; j < 4; ++j) {
            int hw = hwb + j;
            int h = hw / Wdim;
            int w = hw - h * Wdim;
            int own = tt[j] - 1;
            float vy = (float)h + oy[j];
            float vx = (float)w + ox[j];
#pragma unroll
            for (int k = 0; k < Kdim; ++k) {
                float m = (own == k) ? 1.0f : 0.0f;
                acc[k * 5 + 0] += m;
                acc[k * 5 + 1] = fmaf(m, vy, acc[k * 5 + 1]);
                acc[k * 5 + 2] = fmaf(m, vx, acc[k * 5 + 2]);
                acc[k * 5 + 3] = fmaf(m, sy[j], acc[k * 5 + 3]);
                acc[k * 5 + 4] = fmaf(m, sx[j], acc[k * 5 + 4]);
            }
        }
    }

    // fold across half-waves: lanes 0-31 own values 0..39, lanes 32-63 own 40..79
    bool lo = (lane < 32);
#pragma unroll
    for (int v = 0; v < 40; ++v) {
        float send = lo ? acc[v + 40] : acc[v];
        float got = __shfl_xor(send, 32);
        acc[v] += lo ? got : 0.f;
        acc[v + 40] += lo ? 0.f : got;
    }
#pragma unroll
    for (int v = 0; v < 40; ++v) {
        float x = lo ? acc[v] : acc[v + 40];
#pragma unroll
        for (int o = 16; o >= 1; o >>= 1) x += __shfl_xor(x, o);
        if ((lane & 31) == 0) lpart[wv][lo ? v : v + 40] = x;
    }
    __syncthreads();
    if (threadIdx.x < 80) {
        float v = lpart[0][threadIdx.x] + lpart[1][threadIdx.x] +
                  lpart[2][threadIdx.x] + lpart[3][threadIdx.x];
        ws[SPART_OFF + (size_t)(b * NSB + blockIdx.x) * 80 + threadIdx.x] = v;
    }
}

__global__ void k_centers(float* __restrict__ ws) {
    int t = threadIdx.x;  // 320 threads
    int b = t / 80, idx = t - b * 80;
    float s = 0.f;
    const float* sp = ws + SPART_OFF + (size_t)b * NSB * 80 + idx;
    for (int j = 0; j < NSB; ++j) s += sp[j * 80];
    ws[ACC_OFF + t] = s;
    __syncthreads();
    if (t < 64) {
        float cnt = ws[ACC_OFF + t * 5];
        float safe = fmaxf(cnt, 1.0f);
        ws[CK_OFF + t * 2 + 0] = ws[ACC_OFF + t * 5 + 1] / safe;
        ws[CK_OFF + t * 2 + 1] = ws[ACC_OFF + t * 5 + 2] / safe;
        int bb = t >> 4, kk = t & 15;
        float* mw = ws + MSW_OFF + (size_t)(bb * 17 + kk) * 4;
        mw[0] = ws[ACC_OFF + t * 5 + 3] / safe;
        mw[1] = ws[ACC_OFF + t * 5 + 4] / safe;
        mw[2] = (cnt > 0.f) ? 0.5f / cnt : 0.f;
        mw[3] = 0.f;
    }
    if (t >= 64 && t < 68) {
        float* mw = ws + MSW_OFF + (size_t)((t - 64) * 17 + 16) * 4;
        mw[0] = mw[1] = mw[2] = mw[3] = 0.f;
    }
    __syncthreads();
    if (t == 0) {
        float s2 = 0.f;
        for (int j = 0; j < 64; ++j) s2 += (ws[ACC_OFF + j * 5] > 0.f) ? 1.f : 0.f;
        ws[NPRES_OFF] = fmaxf(s2, 1.0f);
    }
}

__global__ __launch_bounds__(256, 3) void k_main(const float* __restrict__ yp,
                                                 const int* __restrict__ yt,
                                                 float* __restrict__ ws,
                                                 unsigned* __restrict__ hist) {
    int b = blockIdx.y;
    int lane = threadIdx.x & 63;
    int wv = threadIdx.x >> 6;
    __shared__ float ck_s[32];
    __shared__ float4 msw_s[17];
    __shared__ float part[4][2];
    if (threadIdx.x < 32) ck_s[threadIdx.x] = ws[CK_OFF + b * 32 + threadIdx.x];
    if (threadIdx.x < 17)
        msw_s[threadIdx.x] = ((const float4*)(ws + MSW_OFF))[b * 17 + threadIdx.x];
    __syncthreads();

    float cky[Kdim], ckx[Kdim];
#pragma unroll
    for (int k = 0; k < Kdim; ++k) {
        cky[k] = ck_s[k * 2];
        ckx[k] = ck_s[k * 2 + 1];
    }

    unsigned* hb = hist + (size_t)(b * Kdim) * 2 * NBINS;
    unsigned* posnh = hist + (size_t)NHIST;
    const float4* bp4 = (const float4*)(yp + (size_t)b * 5 * HWPIX);
    const int4* bt4 = (const int4*)(yt + (size_t)b * HWPIX);

    float varsum = 0.f, ssum = 0.f;
    for (int p = 0; p < 3; ++p) {
        int g = p * GPI + blockIdx.x * 256 + threadIdx.x;
        float4 voy = bp4[g];
        float4 vox = bp4[g + Q4];
        float4 vsy = bp4[g + 2 * Q4];
        float4 vsx = bp4[g + 3 * Q4];
        float4 vse = bp4[g + 4 * Q4];
        int4 vt = bt4[g];
        int hwb = g * 4;
        float oy[4] = {voy.x, voy.y, voy.z, voy.w};
        float ox[4] = {vox.x, vox.y, vox.z, vox.w};
        float sya[4] = {vsy.x, vsy.y, vsy.z, vsy.w};
        float sxa[4] = {vsx.x, vsx.y, vsx.z, vsx.w};
        float sea[4] = {vse.x, vse.y, vse.z, vse.w};
        int tt[4] = {vt.x, vt.y, vt.z, vt.w};
#pragma unroll
        for (int j = 0; j < 4; ++j) {
            int hw = hwb + j;
            int h = hw / Wdim;
            int w = hw - h * Wdim;
            int own = tt[j] - 1;
            float sy = sya[j], sx = sxa[j];
            float ey = (float)h + oy[j], ex = (float)w + ox[j];
            float sby = fmaxf(sy, EPSf), sbx = fmaxf(sx, EPSf);
            float iy = 0.5f / (sby * sby), ix = 0.5f / (sbx * sbx);

            unsigned sm = 0;
#pragma unroll
            for (int k = 0; k < Kdim; ++k) {
                float dy = ey - cky[k];
                float dx = ex - ckx[k];
                float q = fmaf(dy * dy, iy, dx * dx * ix);
                if (q < QCLIP) sm |= (1u << k);
            }
            // dev + var contribution (slot 16 = zeros for unlabeled)
            int ow = (own >= 0) ? own : 16;
            float4 mw = msw_s[ow];
            float devv = fabsf(sy - mw.x) + fabsf(sx - mw.y);
            varsum = fmaf(devv, mw.z, varsum);

            float st = (own >= 0) ? EPSf : 0.f;
            while (sm) {  // rare slow path
                int k = __ffs(sm) - 1;
                sm &= sm - 1;
                float dy = ey - ck_s[k * 2];
                float dx = ex - ck_s[k * 2 + 1];
                float q = fmaf(dy * dy, iy, dx * dx * ix);
                float phi = expf(-q);
                phi = fminf(fmaxf(phi, EPSf), 1.0f - EPSf);
                float lg = logf(phi) - log1pf(-phi);
                bool isPos = (k == own);
                float e;
                if (isPos) {
                    st = phi;
                    atomicAdd(&posnh[b * Kdim + k], 1u);
                    e = 1.0f - lg;
                } else {
                    e = 1.0f + lg;
                }
                if (e > 0.f) {
                    int bin = (int)(e * INV_BIN_W);
                    if (bin > NBINS - 1) bin = NBINS - 1;
                    atomicAdd(&hb[(k * 2 + (isPos ? 1 : 0)) * NBINS + bin], 1u);
                }
            }
            float dd = sea[j] - st;
            ssum = fmaf(dd, dd, ssum);
        }
    }
#pragma unroll
    for (int o = 32; o >= 1; o >>= 1) {
        varsum += __shfl_xor(varsum, o);
        ssum += __shfl_xor(ssum, o);
    }
    if (lane == 0) {
        part[wv][0] = varsum;
        part[wv][1] = ssum;
    }
    __syncthreads();
    if (threadIdx.x < 2) {
        float v = part[0][threadIdx.x] + part[1][threadIdx.x] +
                  part[2][threadIdx.x] + part[3][threadIdx.x];
        ws[MPART_OFF + (size_t)(b * NSB + blockIdx.x) * 2 + threadIdx.x] = v;
    }
}

__global__ void k_lovasz(float* __restrict__ ws, const unsigned* __restrict__ hist) {
    int i = blockIdx.x;  // 0..63
    int lane = threadIdx.x;
    float P = ws[ACC_OFF + i * 5];
    if (P < 0.5f) {
        if (lane == 0) ws[LOVARR_OFF + i] = 0.f;
        return;
    }
    const unsigned* hn = hist + (size_t)i * 2 * NBINS;
    const unsigned* hp = hn + NBINS;
    const unsigned* posnh = hist + (size_t)NHIST;
    const float C_LO = logf(EPSf) - log1pf(-EPSf);
    const int HOTBIN = (int)((1.0f - C_LO) * INV_BIN_W);
    int deficit = (int)(P + 0.5f) - (int)posnh[i];
    int carry_p = 0, carry_n = 0;
    float Jtop = 0.f;
    float trap = 0.f;
    for (int c = NBINS / 64 - 1; c >= 0; --c) {
        int m = c * 64 + lane;
        int vp = (int)hp[m];
        int vn = (int)hn[m];
        if (m == HOTBIN) vp += deficit;
        for (int o = 1; o < 64; o <<= 1) {
            int tp = __shfl_down(vp, o);
            int tn = __shfl_down(vn, o);
            if (lane + o < 64) { vp += tp; vn += tn; }
        }
        float p_edge = (float)(carry_p + vp);
        float n_edge = (float)(carry_n + vn);
        float J = 1.0f - (P - p_edge) / (P + n_edge);
        float Jn = __shfl_down(J, 1);
        if (lane == 63) Jn = Jtop;
        trap += 0.5f * (J + Jn);
        carry_p += __shfl(vp, 0);
        carry_n += __shfl(vn, 0);
        Jtop = __shfl(J, 0);
    }
    for (int o = 1; o < 64; o <<= 1) {
        float t2 = __shfl_down(trap, o);
        if (lane + o < 64) trap += t2;
    }
    if (lane == 0) ws[LOVARR_OFF + i] = trap * BIN_W;
}

__global__ void k_final(const float* __restrict__ ws, float* __restrict__ out) {
    __shared__ float r0[256], r1[256], r2[256];
    int t = threadIdx.x;
    float v = 0.f, s = 0.f, l = 0.f;
    for (int j = t; j < Bdim * NSB; j += 256) {
        v += ws[MPART_OFF + 2 * j];
        s += ws[MPART_OFF + 2 * j + 1];
    }
    if (t < 64) l = ws[LOVARR_OFF + t];
    r0[t] = v; r1[t] = s; r2[t] = l;
    __syncthreads();
    for (int o = 128; o > 0; o >>= 1) {
        if (t < o) { r0[t] += r0[t + o]; r1[t] += r1[t + o]; r2[t] += r2[t + o]; }
        __syncthreads();
    }
    if (t == 0) {
        float npres = ws[NPRES_OFF];
        out[0] = r2[0] / npres + 10.0f * (r0[0] / npres) +
                 r1[0] / (float)((size_t)Bdim * HWPIX);
    }
}

extern "C" void kernel_launch(void* const* d_in, const int* in_sizes, int n_in,
                              void* d_out, int out_size, void* d_ws, size_t ws_size,
                              hipStream_t stream) {
    const float* yp = (const float*)d_in[0];
    const int* yt = (const int*)d_in[1];
    float* ws = (float*)d_ws;
    unsigned* hist = (unsigned*)((char*)d_ws + HIST_OFF_F * 4);

    dim3 g(NSB, Bdim);
    k_stats<<<g, 256, 0, stream>>>(yp, yt, ws, hist);
    k_centers<<<1, 320, 0, stream>>>(ws);
    k_main<<<g, 256, 0, stream>>>(yp, yt, ws, hist);
    k_lovasz<<<64, 64, 0, stream>>>(ws, hist);
    k_final<<<1, 256, 0, stream>>>(ws, (float*)d_out);
}

// Round 6
// 83.262 us; speedup vs baseline: 5.5617x; 1.0467x over previous
//
#include <hip/hip_runtime.h>

typedef float f32x2 __attribute__((ext_vector_type(2)));

#define HWPIX 589824
#define Wdim 768
#define Bdim 4
#define Kdim 16
#define NBINS 2048
#define RANGE_F 16.0f
#define BIN_W (RANGE_F / NBINS)
#define INV_BIN_W (NBINS / RANGE_F)
#define EPSf 1e-6f
#define QCLIP 13.8155106f   /* -log(1e-6): q >= QCLIP  <=>  phi clamps to EPS */

#define Q4 (HWPIX / 4)                 // 147456 float4 groups per channel

// k_stats geometry: 192 blocks/batch, 12 px/thread (3 float4 iters)
#define NSB_S 192
#define GPI_S (NSB_S * 256)
#define NTHREADS_S (NSB_S * Bdim * 256)
// k_main geometry: 288 blocks/batch, 8 px/thread (2 float4 iters)
#define NSB_M 288
#define GPI_M (NSB_M * 256)

// ws float offsets
#define ACC_OFF 0                      // [B][K][5]
#define LOVARR_OFF 724                 // [64]
#define HIST_OFF_F 1024                // uint hist[B*K][2][NBINS]
#define NHIST (Bdim * Kdim * 2 * NBINS)
#define POSNH_OFF_F (HIST_OFF_F + NHIST)
#define SPART_OFF (POSNH_OFF_F + 64)   // float [B*NSB_S][80]
#define MPART_OFF (SPART_OFF + Bdim * NSB_S * 80)  // float [B*NSB_M][2]

__global__ __launch_bounds__(256, 3) void k_stats(const float* __restrict__ yp,
                                                  const int* __restrict__ yt,
                                                  float* __restrict__ ws,
                                                  unsigned* __restrict__ hist) {
    int b = blockIdx.y;
    int lane = threadIdx.x & 63;
    int wv = threadIdx.x >> 6;
    __shared__ float lpart[4][80];

    // zero hist + posnh (folded memset)
    {
        int gtid = (blockIdx.y * NSB_S + blockIdx.x) * 256 + threadIdx.x;
        for (int i = gtid; i < NHIST + 64; i += NTHREADS_S) hist[i] = 0u;
    }

    const float4* bp4 = (const float4*)(yp + (size_t)b * 5 * HWPIX);
    const int4* bt4 = (const int4*)(yt + (size_t)b * HWPIX);

    // acc2[j*5+c] = component c for k-pair {2j, 2j+1}
    f32x2 acc2[40];
#pragma unroll
    for (int v = 0; v < 40; ++v) acc2[v] = (f32x2){0.f, 0.f};

    for (int p = 0; p < 3; ++p) {
        int g = p * GPI_S + blockIdx.x * 256 + threadIdx.x;
        float4 voy = bp4[g];
        float4 vox = bp4[g + Q4];
        float4 vsy = bp4[g + 2 * Q4];
        float4 vsx = bp4[g + 3 * Q4];
        int4 vt = bt4[g];
        int hwb = g * 4;
        float oy[4] = {voy.x, voy.y, voy.z, voy.w};
        float ox[4] = {vox.x, vox.y, vox.z, vox.w};
        float sy[4] = {vsy.x, vsy.y, vsy.z, vsy.w};
        float sx[4] = {vsx.x, vsx.y, vsx.z, vsx.w};
        int tt[4] = {vt.x, vt.y, vt.z, vt.w};
#pragma unroll
        for (int j = 0; j < 4; ++j) {
            int hw = hwb + j;
            int h = hw / Wdim;
            int w = hw - h * Wdim;
            int own = tt[j] - 1;
            float vy = (float)h + oy[j];
            float vx = (float)w + ox[j];
#pragma unroll
            for (int q = 0; q < 8; ++q) {
                f32x2 m2 = {(own == 2 * q) ? 1.0f : 0.0f,
                            (own == 2 * q + 1) ? 1.0f : 0.0f};
                acc2[q * 5 + 0] += m2;
                acc2[q * 5 + 1] += m2 * vy;
                acc2[q * 5 + 2] += m2 * vx;
                acc2[q * 5 + 3] += m2 * sy[j];
                acc2[q * 5 + 4] += m2 * sx[j];
            }
        }
    }

    // flatten acc2 -> logical acc[v], v = k*5+c, k=2q+e
#define ACCV(v) (acc2[((v) / 5 / 2) * 5 + (v) % 5][((v) / 5) & 1])

    // fold across half-waves: lanes 0-31 own values 0..39, lanes 32-63 own 40..79
    bool lo = (lane < 32);
#pragma unroll
    for (int v = 0; v < 40; ++v) {
        float send = lo ? ACCV(v + 40) : ACCV(v);
        float got = __shfl_xor(send, 32);
        ACCV(v) += lo ? got : 0.f;
        ACCV(v + 40) += lo ? 0.f : got;
    }
#pragma unroll
    for (int v = 0; v < 40; ++v) {
        float x = lo ? ACCV(v) : ACCV(v + 40);
#pragma unroll
        for (int o = 16; o >= 1; o >>= 1) x += __shfl_xor(x, o);
        if ((lane & 31) == 0) lpart[wv][lo ? v : v + 40] = x;
    }
    __syncthreads();
    if (threadIdx.x < 80) {
        float v = lpart[0][threadIdx.x] + lpart[1][threadIdx.x] +
                  lpart[2][threadIdx.x] + lpart[3][threadIdx.x];
        ws[SPART_OFF + (size_t)(b * NSB_S + blockIdx.x) * 80 + threadIdx.x] = v;
    }
#undef ACCV
}

// 80 blocks x 256: one wave per output (320 outputs); lane sums 3 strided
// partials, butterfly-reduces, lane 0 stores ACC.
__global__ void k_centers2(float* __restrict__ ws) {
    int wv = threadIdx.x >> 6;
    int lane = threadIdx.x & 63;
    int gw = blockIdx.x * 4 + wv;        // 0..319
    int b = gw / 80, idx = gw - b * 80;
    const float* sp = ws + SPART_OFF + (size_t)b * NSB_S * 80 + idx;
    float x = sp[(size_t)lane * 80] + sp[(size_t)(lane + 64) * 80] +
              sp[(size_t)(lane + 128) * 80];
#pragma unroll
    for (int o = 32; o >= 1; o >>= 1) x += __shfl_xor(x, o);
    if (lane == 0) ws[ACC_OFF + b * 80 + idx] = x;
}

__global__ __launch_bounds__(256, 4) void k_main(const float* __restrict__ yp,
                                                 const int* __restrict__ yt,
                                                 float* __restrict__ ws,
                                                 unsigned* __restrict__ hist) {
    int b = blockIdx.y;
    int lane = threadIdx.x & 63;
    int wv = threadIdx.x >> 6;
    __shared__ float ck_s[32];
    __shared__ float4 msw_s[17];
    __shared__ float part[4][2];
    // prologue: compute centers/means/weights for this batch from ACC
    if (threadIdx.x < 16) {
        int k = threadIdx.x;
        const float* a = ws + ACC_OFF + (size_t)b * 80 + k * 5;
        float cnt = a[0];
        float safe = fmaxf(cnt, 1.0f);
        float inv = 1.0f / safe;
        ck_s[k * 2 + 0] = a[1] * inv;
        ck_s[k * 2 + 1] = a[2] * inv;
        float4 mw;
        mw.x = a[3] * inv;
        mw.y = a[4] * inv;
        mw.z = (cnt > 0.f) ? 0.5f / cnt : 0.f;
        mw.w = 0.f;
        msw_s[k] = mw;
    }
    if (threadIdx.x == 16) msw_s[16] = (float4){0.f, 0.f, 0.f, 0.f};
    __syncthreads();

    f32x2 cky2[8], ckx2[8];
#pragma unroll
    for (int q = 0; q < 8; ++q) {
        cky2[q] = (f32x2){ck_s[4 * q], ck_s[4 * q + 2]};
        ckx2[q] = (f32x2){ck_s[4 * q + 1], ck_s[4 * q + 3]};
    }

    unsigned* hb = hist + (size_t)(b * Kdim) * 2 * NBINS;
    unsigned* posnh = hist + (size_t)NHIST;
    const float4* bp4 = (const float4*)(yp + (size_t)b * 5 * HWPIX);
    const int4* bt4 = (const int4*)(yt + (size_t)b * HWPIX);

    float varsum = 0.f, ssum = 0.f;
    for (int p = 0; p < 2; ++p) {
        int g = p * GPI_M + blockIdx.x * 256 + threadIdx.x;
        float4 voy = bp4[g];
        float4 vox = bp4[g + Q4];
        float4 vsy = bp4[g + 2 * Q4];
        float4 vsx = bp4[g + 3 * Q4];
        float4 vse = bp4[g + 4 * Q4];
        int4 vt = bt4[g];
        int hwb = g * 4;
        float oy[4] = {voy.x, voy.y, voy.z, voy.w};
        float ox[4] = {vox.x, vox.y, vox.z, vox.w};
        float sya[4] = {vsy.x, vsy.y, vsy.z, vsy.w};
        float sxa[4] = {vsx.x, vsx.y, vsx.z, vsx.w};
        float sea[4] = {vse.x, vse.y, vse.z, vse.w};
        int tt[4] = {vt.x, vt.y, vt.z, vt.w};
#pragma unroll
        for (int j = 0; j < 4; ++j) {
            int hw = hwb + j;
            int h = hw / Wdim;
            int w = hw - h * Wdim;
            int own = tt[j] - 1;
            float sy = sya[j], sx = sxa[j];
            float ey = (float)h + oy[j], ex = (float)w + ox[j];
            float sby = fmaxf(sy, EPSf), sbx = fmaxf(sx, EPSf);
            float iy = 0.5f / (sby * sby), ix = 0.5f / (sbx * sbx);

            unsigned sm = 0;
#pragma unroll
            for (int q = 0; q < 8; ++q) {
                f32x2 dy2 = ey - cky2[q];
                f32x2 dx2 = ex - ckx2[q];
                f32x2 q2 = dy2 * dy2 * iy + dx2 * dx2 * ix;
                if (q2.x < QCLIP) sm |= (1u << (2 * q));
                if (q2.y < QCLIP) sm |= (1u << (2 * q + 1));
            }
            int ow = (own >= 0) ? own : 16;
            float4 mw = msw_s[ow];
            float devv = fabsf(sy - mw.x) + fabsf(sx - mw.y);
            varsum = fmaf(devv, mw.z, varsum);

            float st = (own >= 0) ? EPSf : 0.f;
            while (sm) {  // rare slow path
                int k = __ffs(sm) - 1;
                sm &= sm - 1;
                float dy = ey - ck_s[k * 2];
                float dx = ex - ck_s[k * 2 + 1];
                float q = fmaf(dy * dy, iy, dx * dx * ix);
                float phi = expf(-q);
                phi = fminf(fmaxf(phi, EPSf), 1.0f - EPSf);
                float lg = logf(phi) - log1pf(-phi);
                bool isPos = (k == own);
                float e;
                if (isPos) {
                    st = phi;
                    atomicAdd(&posnh[b * Kdim + k], 1u);
                    e = 1.0f - lg;
                } else {
                    e = 1.0f + lg;
                }
                if (e > 0.f) {
                    int bin = (int)(e * INV_BIN_W);
                    if (bin > NBINS - 1) bin = NBINS - 1;
                    atomicAdd(&hb[(k * 2 + (isPos ? 1 : 0)) * NBINS + bin], 1u);
                }
            }
            float dd = sea[j] - st;
            ssum = fmaf(dd, dd, ssum);
        }
    }
#pragma unroll
    for (int o = 32; o >= 1; o >>= 1) {
        varsum += __shfl_xor(varsum, o);
        ssum += __shfl_xor(ssum, o);
    }
    if (lane == 0) {
        part[wv][0] = varsum;
        part[wv][1] = ssum;
    }
    __syncthreads();
    if (threadIdx.x < 2) {
        float v = part[0][threadIdx.x] + part[1][threadIdx.x] +
                  part[2][threadIdx.x] + part[3][threadIdx.x];
        ws[MPART_OFF + (size_t)(b * NSB_M + blockIdx.x) * 2 + threadIdx.x] = v;
    }
}

__global__ void k_lovasz(float* __restrict__ ws, const unsigned* __restrict__ hist) {
    int i = blockIdx.x;  // 0..63
    int lane = threadIdx.x;
    float P = ws[ACC_OFF + i * 5];
    if (P < 0.5f) {
        if (lane == 0) ws[LOVARR_OFF + i] = 0.f;
        return;
    }
    const unsigned* hn = hist + (size_t)i * 2 * NBINS;
    const unsigned* hp = hn + NBINS;
    const unsigned* posnh = hist + (size_t)NHIST;
    const float C_LO = logf(EPSf) - log1pf(-EPSf);
    const int HOTBIN = (int)((1.0f - C_LO) * INV_BIN_W);
    int deficit = (int)(P + 0.5f) - (int)posnh[i];
    int carry_p = 0, carry_n = 0;
    float Jtop = 0.f;
    float trap = 0.f;
    for (int c = NBINS / 64 - 1; c >= 0; --c) {
        int m = c * 64 + lane;
        int vp = (int)hp[m];
        int vn = (int)hn[m];
        if (m == HOTBIN) vp += deficit;
        for (int o = 1; o < 64; o <<= 1) {
            int tp = __shfl_down(vp, o);
            int tn = __shfl_down(vn, o);
            if (lane + o < 64) { vp += tp; vn += tn; }
        }
        float p_edge = (float)(carry_p + vp);
        float n_edge = (float)(carry_n + vn);
        float J = 1.0f - (P - p_edge) / (P + n_edge);
        float Jn = __shfl_down(J, 1);
        if (lane == 63) Jn = Jtop;
        trap += 0.5f * (J + Jn);
        carry_p += __shfl(vp, 0);
        carry_n += __shfl(vn, 0);
        Jtop = __shfl(J, 0);
    }
    for (int o = 1; o < 64; o <<= 1) {
        float t2 = __shfl_down(trap, o);
        if (lane + o < 64) trap += t2;
    }
    if (lane == 0) ws[LOVARR_OFF + i] = trap * BIN_W;
}

__global__ void k_final(const float* __restrict__ ws, float* __restrict__ out) {
    __shared__ float r0[256], r1[256], r2[256], r3[256];
    int t = threadIdx.x;
    float v = 0.f, s = 0.f, l = 0.f, pr = 0.f;
    for (int j = t; j < Bdim * NSB_M; j += 256) {
        v += ws[MPART_OFF + 2 * j];
        s += ws[MPART_OFF + 2 * j + 1];
    }
    if (t < 64) {
        l = ws[LOVARR_OFF + t];
        pr = (ws[ACC_OFF + t * 5] > 0.f) ? 1.f : 0.f;
    }
    r0[t] = v; r1[t] = s; r2[t] = l; r3[t] = pr;
    __syncthreads();
    for (int o = 128; o > 0; o >>= 1) {
        if (t < o) {
            r0[t] += r0[t + o]; r1[t] += r1[t + o];
            r2[t] += r2[t + o]; r3[t] += r3[t + o];
        }
        __syncthreads();
    }
    if (t == 0) {
        float npres = fmaxf(r3[0], 1.0f);
        out[0] = r2[0] / npres + 10.0f * (r0[0] / npres) +
                 r1[0] / (float)((size_t)Bdim * HWPIX);
    }
}

extern "C" void kernel_launch(void* const* d_in, const int* in_sizes, int n_in,
                              void* d_out, int out_size, void* d_ws, size_t ws_size,
                              hipStream_t stream) {
    const float* yp = (const float*)d_in[0];
    const int* yt = (const int*)d_in[1];
    float* ws = (float*)d_ws;
    unsigned* hist = (unsigned*)((char*)d_ws + HIST_OFF_F * 4);

    dim3 gs(NSB_S, Bdim);
    dim3 gm(NSB_M, Bdim);
    k_stats<<<gs, 256, 0, stream>>>(yp, yt, ws, hist);
    k_centers2<<<80, 256, 0, stream>>>(ws);
    k_main<<<gm, 256, 0, stream>>>(yp, yt, ws, hist);
    k_lovasz<<<64, 64, 0, stream>>>(ws, hist);
    k_final<<<1, 256, 0, stream>>>(ws, (float*)d_out);
}